// Round 8
// baseline (35077.759 us; speedup 1.0000x reference)
//
#include <hip/hip_runtime.h>
#include <math.h>

#define Bq 256
#define Tq 200
#define INq 33
#define Hq 2048
#define OUTq 4

#define BK 32
#define NST 16          // stages per K-quarter: 512/32

#define DOT4(ACC, Av, Bv) \
  ACC = fmaf((Av).x, (Bv).x, ACC); ACC = fmaf((Av).y, (Bv).y, ACC); \
  ACC = fmaf((Av).z, (Bv).z, ACC); ACC = fmaf((Av).w, (Bv).w, ACC)

// LDS (float offsets), all padded-33 conflict-free fabrics (R6-proven):
//  A[q][buf] : [32 rows][33] at (q*2+buf)*1056          -> 8448 floats
//  B[q][buf] : [64 cols][33] at 8448 + (q*2+buf)*2112   -> 16896 floats
//  combine   : 3 x (128 thr x 21) stride-21 (coprime 32) overlays A/B post-loop
//  proj scratch: 32 floats at 25344
#define AOFF(q,buf) (((q)*2+(buf))*1056)
#define BOFF(q,buf) (8448 + ((q)*2+(buf))*2112)
#define COMBOFF(p)  ((p)*2688)
#define PSOFF 25344
#define SMEMF 25376

// ---------------------------------------------------------------------------
// tail: out_o[r, tp, :] = softmax(h_row @ Wh2o^T) for the final step
// ---------------------------------------------------------------------------
__global__ __launch_bounds__(256) void proj_tail(
    const float* __restrict__ hbase, size_t rstride,
    const float* __restrict__ Wh2o, float* __restrict__ out_o, int tp)
{
  const int tid = threadIdx.x;
  const int r  = blockIdx.x * 64 + (tid >> 2);
  const int p4 = tid & 3;
  const float* hp = hbase + (size_t)r * rstride;
  float a0 = 0.f, a1 = 0.f, a2 = 0.f, a3 = 0.f;
  const int k0 = p4 * 512;
#pragma unroll 4
  for (int k = k0; k < k0 + 512; k += 4) {
    float4 hv = *(const float4*)(hp + k);
    float4 w0 = *(const float4*)(Wh2o + 0 * Hq + k);
    float4 w1 = *(const float4*)(Wh2o + 1 * Hq + k);
    float4 w2 = *(const float4*)(Wh2o + 2 * Hq + k);
    float4 w3 = *(const float4*)(Wh2o + 3 * Hq + k);
    DOT4(a0, hv, w0); DOT4(a1, hv, w1); DOT4(a2, hv, w2); DOT4(a3, hv, w3);
  }
  a0 += __shfl_xor(a0, 1); a1 += __shfl_xor(a1, 1);
  a2 += __shfl_xor(a2, 1); a3 += __shfl_xor(a3, 1);
  a0 += __shfl_xor(a0, 2); a1 += __shfl_xor(a1, 2);
  a2 += __shfl_xor(a2, 2); a3 += __shfl_xor(a3, 2);
  if (p4 == 0) {
    float m  = fmaxf(fmaxf(a0, a1), fmaxf(a2, a3));
    float e0 = expf(a0 - m), e1 = expf(a1 - m);
    float e2 = expf(a2 - m), e3 = expf(a3 - m);
    float inv = 1.0f / (e0 + e1 + e2 + e3);
    float* op = out_o + ((size_t)r * Tq + tp) * OUTq;
    op[0] = e0 * inv; op[1] = e1 * inv; op[2] = e2 * inv; op[3] = e3 * inv;
  }
}

// ---------------------------------------------------------------------------
// One step. 256 WGs x 512 threads (1 WG/CU, ~101KB LDS).
// R4 structure verbatim (quarter q of 128 thr does k in [512q,512q+512),
// 32x64 tile, 4x4 microtile, reg-prefetch double buffer, fixed-order
// split-K combine) -- only the LDS layouts changed to padded-33
// conflict-free fabrics. FMA order identical to R4 -> bitwise-same output.
// ---------------------------------------------------------------------------
template<bool SLAB>
__global__ __launch_bounds__(512, 1) void rnn_step(
    const float* __restrict__ x, const float* __restrict__ noise,
    const float* __restrict__ Wi2h, const float* __restrict__ Wrec,
    const float* __restrict__ Wh2o, float* __restrict__ out_h,
    float* __restrict__ out_o, const float* __restrict__ slabP,
    float* __restrict__ slabT, int t)
{
  constexpr size_t HSTR = SLAB ? (size_t)Hq : (size_t)Tq * Hq;
  __shared__ float smem[SMEMF];

  const int wg  = blockIdx.x;
  const int tid = threadIdx.x;

  // XCD-chunked swizzle: XCD c owns col-tiles [4c,4c+4) -> Wrec panel L2-hot
  const int L  = (wg & 7) * 32 + (wg >> 3);
  const int TC = L >> 3;          // 0..31 col-tile
  const int TR = L & 7;           // 0..7  row-tile

  const int q  = tid >> 7;        // K-quarter 0..3
  const int qt = tid & 127;
  const int tx = qt & 15;         // n-quad
  const int ty = qt >> 4;         // m-quad (0..7)
  const int m0 = ty * 4, n0 = tx * 4;
  const int b0 = TR * 32 + m0;    // batch row base
  const int j0 = TC * 64 + n0;    // hidden col base
  const int kb = q * 512;

  const float* hPrev = SLAB ? slabP
                            : (out_h + (size_t)(t > 0 ? t - 1 : 0) * Hq);

  // staging maps (per quarter)
  const int sm  = qt & 31;            // A row; k-chunk of 8
  const int skh = (qt >> 5) * 8;
  const int sn  = qt >> 1;            // B col; k-chunk of 16
  const int snk = (qt & 1) * 16;
  const float* gA = hPrev + (size_t)(TR * 32 + sm) * HSTR + kb + skh;
  const float* gB = Wrec + (size_t)(TC * 64 + sn) * Hq + kb + snk;

  float4 sA0, sA1, sB0, sB1, sB2, sB3;
  if (t > 0) {                        // issue stage-0 loads first (overlap proj)
    sA0 = *(const float4*)(gA);      sA1 = *(const float4*)(gA + 4);
    sB0 = *(const float4*)(gB);      sB1 = *(const float4*)(gB + 4);
    sB2 = *(const float4*)(gB + 8);  sB3 = *(const float4*)(gB + 12);
  }

  // ---- softmax head for step t-1, batch row wg (all 512 threads) ----
  if (t > 0) {
    float* ps = smem + PSOFF;
    const int i4 = tid * 4;
    float4 hv = *(const float4*)(hPrev + (size_t)wg * HSTR + i4);
    float4 w0 = *(const float4*)(Wh2o + 0 * Hq + i4);
    float4 w1 = *(const float4*)(Wh2o + 1 * Hq + i4);
    float4 w2 = *(const float4*)(Wh2o + 2 * Hq + i4);
    float4 w3 = *(const float4*)(Wh2o + 3 * Hq + i4);
    float a0 = 0.f, a1 = 0.f, a2 = 0.f, a3 = 0.f;
    DOT4(a0, hv, w0); DOT4(a1, hv, w1); DOT4(a2, hv, w2); DOT4(a3, hv, w3);
#pragma unroll
    for (int m = 1; m <= 32; m <<= 1) {
      a0 += __shfl_xor(a0, m); a1 += __shfl_xor(a1, m);
      a2 += __shfl_xor(a2, m); a3 += __shfl_xor(a3, m);
    }
    if ((tid & 63) == 0) {
      const int w = tid >> 6;
      ps[w * 4 + 0] = a0; ps[w * 4 + 1] = a1;
      ps[w * 4 + 2] = a2; ps[w * 4 + 3] = a3;
    }
    __syncthreads();
    if (tid == 0) {
      float s0 = 0.f, s1 = 0.f, s2 = 0.f, s3 = 0.f;
#pragma unroll
      for (int w = 0; w < 8; ++w) {   // fixed order
        s0 += ps[w * 4 + 0]; s1 += ps[w * 4 + 1];
        s2 += ps[w * 4 + 2]; s3 += ps[w * 4 + 3];
      }
      float m  = fmaxf(fmaxf(s0, s1), fmaxf(s2, s3));
      float e0 = expf(s0 - m), e1 = expf(s1 - m);
      float e2 = expf(s2 - m), e3 = expf(s3 - m);
      float inv = 1.0f / (e0 + e1 + e2 + e3);
      float* op = out_o + ((size_t)wg * Tq + (t - 1)) * OUTq;
      op[0] = e0 * inv; op[1] = e1 * inv; op[2] = e2 * inv; op[3] = e3 * inv;
    }
    __syncthreads();
  }

  float acc00 = 0.f, acc01 = 0.f, acc02 = 0.f, acc03 = 0.f;
  float acc10 = 0.f, acc11 = 0.f, acc12 = 0.f, acc13 = 0.f;
  float acc20 = 0.f, acc21 = 0.f, acc22 = 0.f, acc23 = 0.f;
  float acc30 = 0.f, acc31 = 0.f, acc32 = 0.f, acc33 = 0.f;

  if (t > 0) {
    // prologue: write stage 0 (buf 0) -- padded-33, conflict-free
    {
      float* aL = smem + AOFF(q, 0);
      float* bL = smem + BOFF(q, 0);
      *(float4*)(aL + sm * 33 + skh)      = sA0;
      *(float4*)(aL + sm * 33 + skh + 4)  = sA1;
      *(float4*)(bL + sn * 33 + snk)      = sB0;
      *(float4*)(bL + sn * 33 + snk + 4)  = sB1;
      *(float4*)(bL + sn * 33 + snk + 8)  = sB2;
      *(float4*)(bL + sn * 33 + snk + 12) = sB3;
    }
    __syncthreads();

    for (int s = 0; s < NST; ++s) {
      const int buf = s & 1;
      if (s + 1 < NST) {              // prefetch next stage into regs
        const int o = (s + 1) * BK;
        sA0 = *(const float4*)(gA + o);      sA1 = *(const float4*)(gA + o + 4);
        sB0 = *(const float4*)(gB + o);      sB1 = *(const float4*)(gB + o + 4);
        sB2 = *(const float4*)(gB + o + 8);  sB3 = *(const float4*)(gB + o + 12);
      }
      const float* aR = smem + AOFF(q, buf) + m0 * 33;   // rows m0..m0+3
      const float* bR = smem + BOFF(q, buf) + n0 * 33;   // cols n0..n0+3
#pragma unroll
      for (int k4 = 0; k4 < BK; k4 += 4) {
        float4 A0 = *(const float4*)(aR + 0 * 33 + k4);
        float4 A1 = *(const float4*)(aR + 1 * 33 + k4);
        float4 A2 = *(const float4*)(aR + 2 * 33 + k4);
        float4 A3 = *(const float4*)(aR + 3 * 33 + k4);
        float4 Bv0 = *(const float4*)(bR + 0 * 33 + k4);
        float4 Bv1 = *(const float4*)(bR + 1 * 33 + k4);
        float4 Bv2 = *(const float4*)(bR + 2 * 33 + k4);
        float4 Bv3 = *(const float4*)(bR + 3 * 33 + k4);
        DOT4(acc00, A0, Bv0); DOT4(acc01, A0, Bv1); DOT4(acc02, A0, Bv2); DOT4(acc03, A0, Bv3);
        DOT4(acc10, A1, Bv0); DOT4(acc11, A1, Bv1); DOT4(acc12, A1, Bv2); DOT4(acc13, A1, Bv3);
        DOT4(acc20, A2, Bv0); DOT4(acc21, A2, Bv1); DOT4(acc22, A2, Bv2); DOT4(acc23, A2, Bv3);
        DOT4(acc30, A3, Bv0); DOT4(acc31, A3, Bv1); DOT4(acc32, A3, Bv2); DOT4(acc33, A3, Bv3);
      }
      if (s + 1 < NST) {              // write next stage to other buffer
        float* aL = smem + AOFF(q, buf ^ 1);
        float* bL = smem + BOFF(q, buf ^ 1);
        *(float4*)(aL + sm * 33 + skh)      = sA0;
        *(float4*)(aL + sm * 33 + skh + 4)  = sA1;
        *(float4*)(bL + sn * 33 + snk)      = sB0;
        *(float4*)(bL + sn * 33 + snk + 4)  = sB1;
        *(float4*)(bL + sn * 33 + snk + 8)  = sB2;
        *(float4*)(bL + sn * 33 + snk + 12) = sB3;
      }
      __syncthreads();
    }
  }

  // ---- input projection, i-slice per quarter (same split/order as R4) ----
  {
    const int ilo = q * 8;
    const int ihi = (q == 3) ? INq : (ilo + 8);
    const float* xb = x + (size_t)b0 * Tq * INq + (size_t)t * INq;
    const float* wv = Wi2h + (size_t)j0 * INq;
    const size_t xs = (size_t)Tq * INq;
    for (int i = ilo; i < ihi; ++i) {
      float x0 = xb[i], x1 = xb[xs + i], x2 = xb[2 * xs + i], x3 = xb[3 * xs + i];
      float w0 = wv[i], w1 = wv[INq + i], w2 = wv[2 * INq + i], w3 = wv[3 * INq + i];
      acc00 = fmaf(x0, w0, acc00); acc01 = fmaf(x0, w1, acc01);
      acc02 = fmaf(x0, w2, acc02); acc03 = fmaf(x0, w3, acc03);
      acc10 = fmaf(x1, w0, acc10); acc11 = fmaf(x1, w1, acc11);
      acc12 = fmaf(x1, w2, acc12); acc13 = fmaf(x1, w3, acc13);
      acc20 = fmaf(x2, w0, acc20); acc21 = fmaf(x2, w1, acc21);
      acc22 = fmaf(x2, w2, acc22); acc23 = fmaf(x2, w3, acc23);
      acc30 = fmaf(x3, w0, acc30); acc31 = fmaf(x3, w1, acc31);
      acc32 = fmaf(x3, w2, acc32); acc33 = fmaf(x3, w3, acc33);
    }
  }

  // ---- split-K combine via LDS (fixed order q1,q2,q3), stride 21 ----
  if (q != 0) {
    float* rd = smem + COMBOFF(q - 1) + qt * 21;
    *(float4*)(rd + 0)  = make_float4(acc00, acc01, acc02, acc03);
    *(float4*)(rd + 4)  = make_float4(acc10, acc11, acc12, acc13);
    *(float4*)(rd + 8)  = make_float4(acc20, acc21, acc22, acc23);
    *(float4*)(rd + 12) = make_float4(acc30, acc31, acc32, acc33);
  }
  __syncthreads();

  if (q == 0) {
#pragma unroll
    for (int p = 0; p < 3; ++p) {
      const float* rd = smem + COMBOFF(p) + qt * 21;
      float4 r0 = *(const float4*)(rd + 0),  r1 = *(const float4*)(rd + 4);
      float4 r2 = *(const float4*)(rd + 8),  r3 = *(const float4*)(rd + 12);
      acc00 += r0.x; acc01 += r0.y; acc02 += r0.z; acc03 += r0.w;
      acc10 += r1.x; acc11 += r1.y; acc12 += r1.z; acc13 += r1.w;
      acc20 += r2.x; acc21 += r2.y; acc22 += r2.z; acc23 += r2.w;
      acc30 += r3.x; acc31 += r3.y; acc32 += r3.z; acc33 += r3.w;
    }

    const float* nzb = noise + ((size_t)t * Bq + b0) * Hq + j0;
    float4 nz0 = *(const float4*)(nzb);
    float4 nz1 = *(const float4*)(nzb + Hq);
    float4 nz2 = *(const float4*)(nzb + 2 * Hq);
    float4 nz3 = *(const float4*)(nzb + 3 * Hq);
    float4 hp0 = make_float4(0.f,0.f,0.f,0.f), hp1 = hp0, hp2 = hp0, hp3 = hp0;
    if (t > 0) {
      hp0 = *(const float4*)(hPrev + (size_t)(b0 + 0) * HSTR + j0);
      hp1 = *(const float4*)(hPrev + (size_t)(b0 + 1) * HSTR + j0);
      hp2 = *(const float4*)(hPrev + (size_t)(b0 + 2) * HSTR + j0);
      hp3 = *(const float4*)(hPrev + (size_t)(b0 + 3) * HSTR + j0);
    }

    float4 o0, o1, o2, o3;
    o0.x = fmaf(fmaxf(acc00 + nz0.x, 0.f), 0.1f, 0.9f * hp0.x);
    o0.y = fmaf(fmaxf(acc01 + nz0.y, 0.f), 0.1f, 0.9f * hp0.y);
    o0.z = fmaf(fmaxf(acc02 + nz0.z, 0.f), 0.1f, 0.9f * hp0.z);
    o0.w = fmaf(fmaxf(acc03 + nz0.w, 0.f), 0.1f, 0.9f * hp0.w);
    o1.x = fmaf(fmaxf(acc10 + nz1.x, 0.f), 0.1f, 0.9f * hp1.x);
    o1.y = fmaf(fmaxf(acc11 + nz1.y, 0.f), 0.1f, 0.9f * hp1.y);
    o1.z = fmaf(fmaxf(acc12 + nz1.z, 0.f), 0.1f, 0.9f * hp1.z);
    o1.w = fmaf(fmaxf(acc13 + nz1.w, 0.f), 0.1f, 0.9f * hp1.w);
    o2.x = fmaf(fmaxf(acc20 + nz2.x, 0.f), 0.1f, 0.9f * hp2.x);
    o2.y = fmaf(fmaxf(acc21 + nz2.y, 0.f), 0.1f, 0.9f * hp2.y);
    o2.z = fmaf(fmaxf(acc22 + nz2.z, 0.f), 0.1f, 0.9f * hp2.z);
    o2.w = fmaf(fmaxf(acc23 + nz2.w, 0.f), 0.1f, 0.9f * hp2.w);
    o3.x = fmaf(fmaxf(acc30 + nz3.x, 0.f), 0.1f, 0.9f * hp3.x);
    o3.y = fmaf(fmaxf(acc31 + nz3.y, 0.f), 0.1f, 0.9f * hp3.y);
    o3.z = fmaf(fmaxf(acc32 + nz3.z, 0.f), 0.1f, 0.9f * hp3.z);
    o3.w = fmaf(fmaxf(acc33 + nz3.w, 0.f), 0.1f, 0.9f * hp3.w);

    float* oh = out_h + (size_t)b0 * Tq * Hq + (size_t)t * Hq + j0;
    *(float4*)(oh)                       = o0;
    *(float4*)(oh + (size_t)Tq * Hq)     = o1;
    *(float4*)(oh + (size_t)2 * Tq * Hq) = o2;
    *(float4*)(oh + (size_t)3 * Tq * Hq) = o3;
    if (SLAB) {
      float* sl = slabT + (size_t)b0 * Hq + j0;
      *(float4*)(sl)            = o0;
      *(float4*)(sl + Hq)       = o1;
      *(float4*)(sl + 2 * Hq)   = o2;
      *(float4*)(sl + 3 * Hq)   = o3;
    }
  }
}

extern "C" void kernel_launch(void* const* d_in, const int* in_sizes, int n_in,
                              void* d_out, int out_size, void* d_ws, size_t ws_size,
                              hipStream_t stream) {
  const float* x     = (const float*)d_in[0];
  const float* noise = (const float*)d_in[1];
  const float* Wi2h  = (const float*)d_in[2];
  const float* Wrec  = (const float*)d_in[3];
  const float* Wh2o  = (const float*)d_in[4];
  float* out_h = (float*)d_out;
  float* out_o = out_h + (size_t)Bq * Tq * Hq;

  const bool use_ws = ws_size >= (size_t)2 * Bq * Hq * sizeof(float);
  float* slab0 = (float*)d_ws;
  float* slab1 = slab0 + (size_t)Bq * Hq;

  if (use_ws) {
    for (int t = 0; t < Tq; ++t) {
      const float* sp = (t > 0) ? (((t - 1) & 1) ? slab1 : slab0) : nullptr;
      float*       st = (t & 1) ? slab1 : slab0;
      rnn_step<true><<<256, 512, 0, stream>>>(x, noise, Wi2h, Wrec, Wh2o,
                                              out_h, out_o, sp, st, t);
    }
    const float* hb = ((Tq - 1) & 1) ? slab1 : slab0;
    proj_tail<<<4, 256, 0, stream>>>(hb, (size_t)Hq, Wh2o, out_o, Tq - 1);
  } else {
    for (int t = 0; t < Tq; ++t) {
      rnn_step<false><<<256, 512, 0, stream>>>(x, noise, Wi2h, Wrec, Wh2o,
                                               out_h, out_o, nullptr, nullptr, t);
    }
    proj_tail<<<4, 256, 0, stream>>>(out_h + (size_t)(Tq - 1) * Hq,
                                     (size_t)Tq * Hq, Wh2o, out_o, Tq - 1);
  }
}

// Round 9
// 10196.556 us; speedup vs baseline: 3.4402x; 3.4402x over previous
//
#include <hip/hip_runtime.h>
#include <math.h>

#define Bq 256
#define Tq 200
#define INq 33
#define Hq 2048
#define OUTq 4

#define BKq 32
#define NST 16          // stages per K-quarter: 512 / 32

#define DOT4(ACC, Av, Bv) \
  ACC = fmaf((Av).x, (Bv).x, ACC); ACC = fmaf((Av).y, (Bv).y, ACC); \
  ACC = fmaf((Av).z, (Bv).z, ACC); ACC = fmaf((Av).w, (Bv).w, ACC)

// XOR swizzle inside a 32-float row; key is a multiple of 4 -> b128 alignment kept
__device__ __forceinline__ int swz(int row, int k) {
  return k ^ (((row >> 2) & 7) << 2);
}

// ---------------------------------------------------------------------------
// tail: out_o[r, tp, :] = softmax(h_row @ Wh2o^T) for the final step
// ---------------------------------------------------------------------------
__global__ __launch_bounds__(256) void proj_tail(
    const float* __restrict__ hbase, size_t rstride,
    const float* __restrict__ Wh2o, float* __restrict__ out_o, int tp)
{
  const int tid = threadIdx.x;
  const int r  = blockIdx.x * 64 + (tid >> 2);
  const int p4 = tid & 3;
  const float* hp = hbase + (size_t)r * rstride;
  float a0 = 0.f, a1 = 0.f, a2 = 0.f, a3 = 0.f;
  const int k0 = p4 * 512;
#pragma unroll 4
  for (int k = k0; k < k0 + 512; k += 4) {
    float4 hv = *(const float4*)(hp + k);
    float4 w0 = *(const float4*)(Wh2o + 0 * Hq + k);
    float4 w1 = *(const float4*)(Wh2o + 1 * Hq + k);
    float4 w2 = *(const float4*)(Wh2o + 2 * Hq + k);
    float4 w3 = *(const float4*)(Wh2o + 3 * Hq + k);
    DOT4(a0, hv, w0); DOT4(a1, hv, w1); DOT4(a2, hv, w2); DOT4(a3, hv, w3);
  }
  a0 += __shfl_xor(a0, 1); a1 += __shfl_xor(a1, 1);
  a2 += __shfl_xor(a2, 1); a3 += __shfl_xor(a3, 1);
  a0 += __shfl_xor(a0, 2); a1 += __shfl_xor(a1, 2);
  a2 += __shfl_xor(a2, 2); a3 += __shfl_xor(a3, 2);
  if (p4 == 0) {
    float m  = fmaxf(fmaxf(a0, a1), fmaxf(a2, a3));
    float e0 = expf(a0 - m), e1 = expf(a1 - m);
    float e2 = expf(a2 - m), e3 = expf(a3 - m);
    float inv = 1.0f / (e0 + e1 + e2 + e3);
    float* op = out_o + ((size_t)r * Tq + tp) * OUTq;
    op[0] = e0 * inv; op[1] = e1 * inv; op[2] = e2 * inv; op[3] = e3 * inv;
  }
}

// ---------------------------------------------------------------------------
// One step. 256 WGs x 512 threads (1 WG/CU, 96KB LDS). R4 structure verbatim
// (quarter q = 128 thr does k in [512q,512q+512), 32x64 tile, 4x4 microtile,
// XOR-swizzled [row][32] tiles, reg-prefetch double buffer, stride-20 combine).
// ONLY change vs R4: staging thread->(row,chunk) maps permuted so each 8-lane
// issue group writes 8 distinct (row>>2) keys -> 8 distinct bank windows
// (b128 optimum), killing the 8-way staging-write conflicts.
// FMA order identical to R4 -> bitwise-identical output.
// ---------------------------------------------------------------------------
template<bool SLAB>
__global__ __launch_bounds__(512, 2) void rnn_step(
    const float* __restrict__ x, const float* __restrict__ noise,
    const float* __restrict__ Wi2h, const float* __restrict__ Wrec,
    const float* __restrict__ Wh2o, float* __restrict__ out_h,
    float* __restrict__ out_o, const float* __restrict__ slabP,
    float* __restrict__ slabT, int t)
{
  constexpr size_t HSTR = SLAB ? (size_t)Hq : (size_t)Tq * Hq;
  // A[q][buf]: 32x32 at (q*2+buf)*1024            (8192 floats)
  // B[q][buf]: 64x32 at 8192 + (q*2+buf)*2048     (16384 floats)
  // combine: 3 x 2560 stride-20 region, overlays A after the K-loop
  __shared__ float smem[24576];

  const int wg  = blockIdx.x;
  const int tid = threadIdx.x;

  // XCD-chunked swizzle: XCD c owns col-tiles [4c,4c+4) -> Wrec panel L2-hot
  const int L  = (wg & 7) * 32 + (wg >> 3);
  const int TC = L >> 3;          // 0..31 col-tile
  const int TR = L & 7;           // 0..7  row-tile

  const int q  = tid >> 7;        // K-quarter 0..3
  const int qt = tid & 127;
  const int tx = qt & 15;         // n-quad
  const int ty = qt >> 4;         // m-quad (0..7)
  const int m0 = ty * 4, n0 = tx * 4;
  const int b0 = TR * 32 + m0;
  const int j0 = TC * 64 + n0;
  const int kb = q * 512;

  const float* hPrev = SLAB ? slabP
                            : (out_h + (size_t)(t > 0 ? t - 1 : 0) * Hq);

  // ---- staging maps: group-conflict-free permutation ----
  // A: 32 rows x 4 chunks of 8; lanes 8j..8j+7 get sm>>2 = 0..7 (distinct keys)
  const int sm  = ((qt & 7) << 2) | ((qt >> 3) & 3);
  const int skh = ((qt >> 5) & 3) * 8;
  // B: 64 rows x 2 halves of 16; lanes 8j..8j+7 get (sn>>2)&7 = 0..7
  const int sn  = (((qt >> 5) & 1) << 5) | ((qt & 7) << 2) | ((qt >> 3) & 3);
  const int snk = ((qt >> 6) & 1) * 16;

  const float* gA = hPrev + (size_t)(TR * 32 + sm) * HSTR + kb + skh;
  const float* gB = Wrec + (size_t)(TC * 64 + sn) * Hq + kb + snk;

  float4 sA0, sA1, sB0, sB1, sB2, sB3;
  if (t > 0) {                        // issue stage-0 loads first (overlap proj)
    sA0 = *(const float4*)(gA);      sA1 = *(const float4*)(gA + 4);
    sB0 = *(const float4*)(gB);      sB1 = *(const float4*)(gB + 4);
    sB2 = *(const float4*)(gB + 8);  sB3 = *(const float4*)(gB + 12);
  }

  // ---- softmax head for step t-1, batch row wg (all 512 threads) ----
  if (t > 0) {
    const int i4 = tid * 4;
    float4 hv = *(const float4*)(hPrev + (size_t)wg * HSTR + i4);
    float4 w0 = *(const float4*)(Wh2o + 0 * Hq + i4);
    float4 w1 = *(const float4*)(Wh2o + 1 * Hq + i4);
    float4 w2 = *(const float4*)(Wh2o + 2 * Hq + i4);
    float4 w3 = *(const float4*)(Wh2o + 3 * Hq + i4);
    float a0 = 0.f, a1 = 0.f, a2 = 0.f, a3 = 0.f;
    DOT4(a0, hv, w0); DOT4(a1, hv, w1); DOT4(a2, hv, w2); DOT4(a3, hv, w3);
#pragma unroll
    for (int m = 1; m <= 32; m <<= 1) {
      a0 += __shfl_xor(a0, m); a1 += __shfl_xor(a1, m);
      a2 += __shfl_xor(a2, m); a3 += __shfl_xor(a3, m);
    }
    if ((tid & 63) == 0) {
      const int w = tid >> 6;
      smem[w * 4 + 0] = a0; smem[w * 4 + 1] = a1;
      smem[w * 4 + 2] = a2; smem[w * 4 + 3] = a3;
    }
    __syncthreads();
    if (tid == 0) {
      float s0 = 0.f, s1 = 0.f, s2 = 0.f, s3 = 0.f;
#pragma unroll
      for (int w = 0; w < 8; ++w) {   // fixed order
        s0 += smem[w * 4 + 0]; s1 += smem[w * 4 + 1];
        s2 += smem[w * 4 + 2]; s3 += smem[w * 4 + 3];
      }
      float m  = fmaxf(fmaxf(s0, s1), fmaxf(s2, s3));
      float e0 = expf(s0 - m), e1 = expf(s1 - m);
      float e2 = expf(s2 - m), e3 = expf(s3 - m);
      float inv = 1.0f / (e0 + e1 + e2 + e3);
      float* op = out_o + ((size_t)wg * Tq + (t - 1)) * OUTq;
      op[0] = e0 * inv; op[1] = e1 * inv; op[2] = e2 * inv; op[3] = e3 * inv;
    }
    __syncthreads();                  // smem[0..31] dead before staging
  }

  float acc00 = 0.f, acc01 = 0.f, acc02 = 0.f, acc03 = 0.f;
  float acc10 = 0.f, acc11 = 0.f, acc12 = 0.f, acc13 = 0.f;
  float acc20 = 0.f, acc21 = 0.f, acc22 = 0.f, acc23 = 0.f;
  float acc30 = 0.f, acc31 = 0.f, acc32 = 0.f, acc33 = 0.f;

  if (t > 0) {
    // prologue: write stage 0 (buf 0)
    {
      float* aL = smem + q * 2048;
      float* bL = smem + 8192 + q * 4096;
      *(float4*)(aL + sm * 32 + swz(sm, skh))      = sA0;
      *(float4*)(aL + sm * 32 + swz(sm, skh + 4))  = sA1;
      *(float4*)(bL + sn * 32 + swz(sn, snk))      = sB0;
      *(float4*)(bL + sn * 32 + swz(sn, snk + 4))  = sB1;
      *(float4*)(bL + sn * 32 + swz(sn, snk + 8))  = sB2;
      *(float4*)(bL + sn * 32 + swz(sn, snk + 12)) = sB3;
    }
    __syncthreads();

    const int aKey = ty << 2;         // rows m0..m0+3 share row>>2 = ty
    const int bKey = (tx & 7) << 2;   // rows n0..n0+3 share row>>2 (&7)

    for (int s = 0; s < NST; ++s) {
      const int buf = s & 1;
      if (s + 1 < NST) {              // prefetch next stage into regs
        const int o = (s + 1) * BKq;
        sA0 = *(const float4*)(gA + o);      sA1 = *(const float4*)(gA + o + 4);
        sB0 = *(const float4*)(gB + o);      sB1 = *(const float4*)(gB + o + 4);
        sB2 = *(const float4*)(gB + o + 8);  sB3 = *(const float4*)(gB + o + 12);
      }
      const float* aT = smem + q * 2048 + buf * 1024 + ty * 128;
      const float* bT = smem + 8192 + q * 4096 + buf * 2048 + tx * 128;
#pragma unroll
      for (int k4 = 0; k4 < BKq; k4 += 4) {
        const float* ap = aT + (k4 ^ aKey);
        const float* bp = bT + (k4 ^ bKey);
        float4 A0 = *(const float4*)(ap);
        float4 A1 = *(const float4*)(ap + 32);
        float4 A2 = *(const float4*)(ap + 64);
        float4 A3 = *(const float4*)(ap + 96);
        float4 Bv0 = *(const float4*)(bp);
        float4 Bv1 = *(const float4*)(bp + 32);
        float4 Bv2 = *(const float4*)(bp + 64);
        float4 Bv3 = *(const float4*)(bp + 96);
        DOT4(acc00, A0, Bv0); DOT4(acc01, A0, Bv1); DOT4(acc02, A0, Bv2); DOT4(acc03, A0, Bv3);
        DOT4(acc10, A1, Bv0); DOT4(acc11, A1, Bv1); DOT4(acc12, A1, Bv2); DOT4(acc13, A1, Bv3);
        DOT4(acc20, A2, Bv0); DOT4(acc21, A2, Bv1); DOT4(acc22, A2, Bv2); DOT4(acc23, A2, Bv3);
        DOT4(acc30, A3, Bv0); DOT4(acc31, A3, Bv1); DOT4(acc32, A3, Bv2); DOT4(acc33, A3, Bv3);
      }
      if (s + 1 < NST) {              // write next stage to other buffer
        float* aL = smem + q * 2048 + (buf ^ 1) * 1024;
        float* bL = smem + 8192 + q * 4096 + (buf ^ 1) * 2048;
        *(float4*)(aL + sm * 32 + swz(sm, skh))      = sA0;
        *(float4*)(aL + sm * 32 + swz(sm, skh + 4))  = sA1;
        *(float4*)(bL + sn * 32 + swz(sn, snk))      = sB0;
        *(float4*)(bL + sn * 32 + swz(sn, snk + 4))  = sB1;
        *(float4*)(bL + sn * 32 + swz(sn, snk + 8))  = sB2;
        *(float4*)(bL + sn * 32 + swz(sn, snk + 12)) = sB3;
      }
      __syncthreads();
    }
  }

  // ---- input projection, i-slice per quarter (same split/order as R4) ----
  {
    const int ilo = q * 8;
    const int ihi = (q == 3) ? INq : (ilo + 8);
    const float* xb = x + (size_t)b0 * Tq * INq + (size_t)t * INq;
    const float* wv = Wi2h + (size_t)j0 * INq;
    const size_t xs = (size_t)Tq * INq;
    for (int i = ilo; i < ihi; ++i) {
      float x0 = xb[i], x1 = xb[xs + i], x2 = xb[2 * xs + i], x3 = xb[3 * xs + i];
      float w0 = wv[i], w1 = wv[INq + i], w2 = wv[2 * INq + i], w3 = wv[3 * INq + i];
      acc00 = fmaf(x0, w0, acc00); acc01 = fmaf(x0, w1, acc01);
      acc02 = fmaf(x0, w2, acc02); acc03 = fmaf(x0, w3, acc03);
      acc10 = fmaf(x1, w0, acc10); acc11 = fmaf(x1, w1, acc11);
      acc12 = fmaf(x1, w2, acc12); acc13 = fmaf(x1, w3, acc13);
      acc20 = fmaf(x2, w0, acc20); acc21 = fmaf(x2, w1, acc21);
      acc22 = fmaf(x2, w2, acc22); acc23 = fmaf(x2, w3, acc23);
      acc30 = fmaf(x3, w0, acc30); acc31 = fmaf(x3, w1, acc31);
      acc32 = fmaf(x3, w2, acc32); acc33 = fmaf(x3, w3, acc33);
    }
  }

  // ---- split-K combine via LDS (fixed order q1,q2,q3), stride 20 (5 coprime 8) ----
  if (q != 0) {
    float* rd = smem + (q - 1) * 2560 + qt * 20;
    *(float4*)(rd + 0)  = make_float4(acc00, acc01, acc02, acc03);
    *(float4*)(rd + 4)  = make_float4(acc10, acc11, acc12, acc13);
    *(float4*)(rd + 8)  = make_float4(acc20, acc21, acc22, acc23);
    *(float4*)(rd + 12) = make_float4(acc30, acc31, acc32, acc33);
  }
  __syncthreads();

  if (q == 0) {
#pragma unroll
    for (int p = 0; p < 3; ++p) {
      const float* rd = smem + p * 2560 + qt * 20;
      float4 r0 = *(const float4*)(rd + 0),  r1 = *(const float4*)(rd + 4);
      float4 r2 = *(const float4*)(rd + 8),  r3 = *(const float4*)(rd + 12);
      acc00 += r0.x; acc01 += r0.y; acc02 += r0.z; acc03 += r0.w;
      acc10 += r1.x; acc11 += r1.y; acc12 += r1.z; acc13 += r1.w;
      acc20 += r2.x; acc21 += r2.y; acc22 += r2.z; acc23 += r2.w;
      acc30 += r3.x; acc31 += r3.y; acc32 += r3.z; acc33 += r3.w;
    }

    const float* nzb = noise + ((size_t)t * Bq + b0) * Hq + j0;
    float4 nz0 = *(const float4*)(nzb);
    float4 nz1 = *(const float4*)(nzb + Hq);
    float4 nz2 = *(const float4*)(nzb + 2 * Hq);
    float4 nz3 = *(const float4*)(nzb + 3 * Hq);
    float4 hp0 = make_float4(0.f,0.f,0.f,0.f), hp1 = hp0, hp2 = hp0, hp3 = hp0;
    if (t > 0) {
      hp0 = *(const float4*)(hPrev + (size_t)(b0 + 0) * HSTR + j0);
      hp1 = *(const float4*)(hPrev + (size_t)(b0 + 1) * HSTR + j0);
      hp2 = *(const float4*)(hPrev + (size_t)(b0 + 2) * HSTR + j0);
      hp3 = *(const float4*)(hPrev + (size_t)(b0 + 3) * HSTR + j0);
    }

    float4 o0, o1, o2, o3;
    o0.x = fmaf(fmaxf(acc00 + nz0.x, 0.f), 0.1f, 0.9f * hp0.x);
    o0.y = fmaf(fmaxf(acc01 + nz0.y, 0.f), 0.1f, 0.9f * hp0.y);
    o0.z = fmaf(fmaxf(acc02 + nz0.z, 0.f), 0.1f, 0.9f * hp0.z);
    o0.w = fmaf(fmaxf(acc03 + nz0.w, 0.f), 0.1f, 0.9f * hp0.w);
    o1.x = fmaf(fmaxf(acc10 + nz1.x, 0.f), 0.1f, 0.9f * hp1.x);
    o1.y = fmaf(fmaxf(acc11 + nz1.y, 0.f), 0.1f, 0.9f * hp1.y);
    o1.z = fmaf(fmaxf(acc12 + nz1.z, 0.f), 0.1f, 0.9f * hp1.z);
    o1.w = fmaf(fmaxf(acc13 + nz1.w, 0.f), 0.1f, 0.9f * hp1.w);
    o2.x = fmaf(fmaxf(acc20 + nz2.x, 0.f), 0.1f, 0.9f * hp2.x);
    o2.y = fmaf(fmaxf(acc21 + nz2.y, 0.f), 0.1f, 0.9f * hp2.y);
    o2.z = fmaf(fmaxf(acc22 + nz2.z, 0.f), 0.1f, 0.9f * hp2.z);
    o2.w = fmaf(fmaxf(acc23 + nz2.w, 0.f), 0.1f, 0.9f * hp2.w);
    o3.x = fmaf(fmaxf(acc30 + nz3.x, 0.f), 0.1f, 0.9f * hp3.x);
    o3.y = fmaf(fmaxf(acc31 + nz3.y, 0.f), 0.1f, 0.9f * hp3.y);
    o3.z = fmaf(fmaxf(acc32 + nz3.z, 0.f), 0.1f, 0.9f * hp3.z);
    o3.w = fmaf(fmaxf(acc33 + nz3.w, 0.f), 0.1f, 0.9f * hp3.w);

    float* oh = out_h + (size_t)b0 * Tq * Hq + (size_t)t * Hq + j0;
    *(float4*)(oh)                       = o0;
    *(float4*)(oh + (size_t)Tq * Hq)     = o1;
    *(float4*)(oh + (size_t)2 * Tq * Hq) = o2;
    *(float4*)(oh + (size_t)3 * Tq * Hq) = o3;
    if (SLAB) {
      float* sl = slabT + (size_t)b0 * Hq + j0;
      *(float4*)(sl)            = o0;
      *(float4*)(sl + Hq)       = o1;
      *(float4*)(sl + 2 * Hq)   = o2;
      *(float4*)(sl + 3 * Hq)   = o3;
    }
  }
}

extern "C" void kernel_launch(void* const* d_in, const int* in_sizes, int n_in,
                              void* d_out, int out_size, void* d_ws, size_t ws_size,
                              hipStream_t stream) {
  const float* x     = (const float*)d_in[0];
  const float* noise = (const float*)d_in[1];
  const float* Wi2h  = (const float*)d_in[2];
  const float* Wrec  = (const float*)d_in[3];
  const float* Wh2o  = (const float*)d_in[4];
  float* out_h = (float*)d_out;
  float* out_o = out_h + (size_t)Bq * Tq * Hq;

  const bool use_ws = ws_size >= (size_t)2 * Bq * Hq * sizeof(float);
  float* slab0 = (float*)d_ws;
  float* slab1 = slab0 + (size_t)Bq * Hq;

  if (use_ws) {
    for (int t = 0; t < Tq; ++t) {
      const float* sp = (t > 0) ? (((t - 1) & 1) ? slab1 : slab0) : nullptr;
      float*       st = (t & 1) ? slab1 : slab0;
      rnn_step<true><<<256, 512, 0, stream>>>(x, noise, Wi2h, Wrec, Wh2o,
                                              out_h, out_o, sp, st, t);
    }
    const float* hb = ((Tq - 1) & 1) ? slab1 : slab0;
    proj_tail<<<4, 256, 0, stream>>>(hb, (size_t)Hq, Wh2o, out_o, Tq - 1);
  } else {
    for (int t = 0; t < Tq; ++t) {
      rnn_step<false><<<256, 512, 0, stream>>>(x, noise, Wi2h, Wrec, Wh2o,
                                               out_h, out_o, nullptr, nullptr, t);
    }
    proj_tail<<<4, 256, 0, stream>>>(out_h + (size_t)(Tq - 1) * Hq,
                                     (size_t)Tq * Hq, Wh2o, out_o, Tq - 1);
  }
}